// Round 6
// baseline (5049.522 us; speedup 1.0000x reference)
//
#include <hip/hip_runtime.h>
#include <hip/hip_bf16.h>

#define NL  3
#define NB  128
#define NT  256
#define NH  512
#define NH3 1536
#define NBH (NB*NH)      // 65536
#define NM  (NB*NT)      // 32768

typedef __bf16 bf16x8 __attribute__((ext_vector_type(8)));
typedef float  floatx4 __attribute__((ext_vector_type(4)));
typedef int    intx4  __attribute__((ext_vector_type(4)));
typedef __hip_bfloat16 bf16;
typedef unsigned long long u64;

__device__ __forceinline__ floatx4 mfma16(bf16x8 a, bf16x8 b, floatx4 c) {
  return __builtin_amdgcn_mfma_f32_16x16x32_bf16(a, b, c, 0, 0, 0);
}
__device__ __forceinline__ void gload16(const void* g, void* l) {
  __builtin_amdgcn_global_load_lds(
      (const __attribute__((address_space(1))) unsigned int*)g,
      (__attribute__((address_space(3))) unsigned int*)l, 16, 0, 0);
}
__device__ __forceinline__ float fsig(float x)  { return 1.0f / (1.0f + __expf(-x)); }
__device__ __forceinline__ float ftanh(float x) { return 2.0f / (1.0f + __expf(-2.0f*x)) - 1.0f; }
__device__ __forceinline__ float b2f(unsigned short u) {
  unsigned v = (unsigned)u << 16; float f; __builtin_memcpy(&f, &v, 4); return f;
}
__device__ __forceinline__ unsigned short f2b(float f) {
  bf16 h = __float2bfloat16(f); unsigned short u; __builtin_memcpy(&u, &h, 2); return u;
}
__device__ __forceinline__ u64 ald(const u64* p) {
  return __hip_atomic_load(p, __ATOMIC_RELAXED, __HIP_MEMORY_SCOPE_AGENT);
}
__device__ __forceinline__ void ast(u64* p, u64 v) {
  __hip_atomic_store(p, v, __ATOMIC_RELAXED, __HIP_MEMORY_SCOPE_AGENT);
}
__device__ __forceinline__ unsigned aadd(unsigned* p, unsigned v) {
  return __hip_atomic_fetch_add(p, v, __ATOMIC_SEQ_CST, __HIP_MEMORY_SCOPE_AGENT);
}
__device__ __forceinline__ void aor(unsigned* p, unsigned v) {
  __hip_atomic_fetch_or(p, v, __ATOMIC_SEQ_CST, __HIP_MEMORY_SCOPE_AGENT);
}
__device__ __forceinline__ unsigned aldu(const unsigned* p) {
  return __hip_atomic_load(p, __ATOMIC_SEQ_CST, __HIP_MEMORY_SCOPE_AGENT);
}
// XCC (XCD) id of this wave's CU: HW reg 20, bits [3:0] on gfx940+ [measured m09]
__device__ __forceinline__ unsigned get_xcc() {
  unsigned x;
  asm volatile("s_getreg_b32 %0, hwreg(20, 0, 32)" : "=s"(x));
  return x & 7u;
}

// Batched poll, L2-scope: 4x 16B loads of a contiguous 64B line with sc0 (bypass L1,
// served by the XCD's L2 = same-XCD coherence point), single waitcnt -> 1 L2 round trip.
__device__ __forceinline__ void ld64sc0(const void* p, intx4& a, intx4& b, intx4& c, intx4& d) {
  asm volatile(
      "global_load_dwordx4 %0, %4, off sc0\n\t"
      "global_load_dwordx4 %1, %4, off offset:16 sc0\n\t"
      "global_load_dwordx4 %2, %4, off offset:32 sc0\n\t"
      "global_load_dwordx4 %3, %4, off offset:48 sc0\n\t"
      "s_waitcnt vmcnt(0)"
      : "=&v"(a), "=&v"(b), "=&v"(c), "=&v"(d)
      : "v"(p)
      : "memory");
}

// ---------- transpose + cvt weights: fp32 [NL][NH][NH3] -> bf16 [NL][NH3][NH] ----------
__global__ void transpose_cvt_kernel(const float* __restrict__ in, bf16* __restrict__ out) {
  __shared__ float tile[32][33];
  int l = blockIdx.z;
  int n0 = blockIdx.x * 32, k0 = blockIdx.y * 32;
  const float* src = in + (size_t)l * NH * NH3;
  bf16* dst = out + (size_t)l * NH3 * NH;
  int tx = threadIdx.x, ty = threadIdx.y;    // 32 x 8
#pragma unroll
  for (int i = 0; i < 4; i++)
    tile[ty + 8*i][tx] = src[(size_t)(k0 + ty + 8*i) * NH3 + n0 + tx];
  __syncthreads();
#pragma unroll
  for (int i = 0; i < 4; i++)
    dst[(size_t)(n0 + ty + 8*i) * NH + k0 + tx] = __float2bfloat16(tile[tx][ty + 8*i]);
}

// ---------- elementwise fp32 -> bf16 (x input) ----------
__global__ void cvt_x_kernel(const float* __restrict__ in, bf16* __restrict__ out) {
  size_t i = (size_t)blockIdx.x * blockDim.x + threadIdx.x;
  float4 v = ((const float4*)in)[i];
  ushort4 pk;
  pk.x = f2b(v.x); pk.y = f2b(v.y); pk.z = f2b(v.z); pk.w = f2b(v.w);
  ((ushort4*)out)[i] = pk;
}

// ---------- xp GEMM (proven): C[m][n] = A[m]@Bt[n]^T + bias[n], bf16 out ----------
__global__ void __launch_bounds__(256, 2) gemm_xp_kernel(
    const bf16* __restrict__ A, const bf16* __restrict__ Bt,
    const float* __restrict__ bias, bf16* __restrict__ C, int a_mode)
{
  __shared__ char alds[16384];
  __shared__ char blds[16384];
  int tid = threadIdx.x;
  int lane = tid & 63, w = tid >> 6;
  int mblk = blockIdx.x, nblk = blockIdx.y;
  int wm = w >> 1, wn = w & 1;
  int klane = (lane >> 4) * 8;
  int r0 = 2*w*16 + (lane & 15);
  size_t arow0, arow1;
  if (a_mode == 0) {
    arow0 = ((size_t)r0 * NT + mblk) * NH;
    arow1 = ((size_t)(r0 + 16) * NT + mblk) * NH;
  } else {
    arow0 = (size_t)(mblk*128 + r0) * NH;
    arow1 = arow0 + (size_t)16 * NH;
  }
  size_t brow0 = (size_t)(nblk*128 + 2*w*16 + (lane & 15)) * NH;
  size_t brow1 = brow0 + (size_t)16 * NH;

  floatx4 acc[4][4];
#pragma unroll
  for (int i = 0; i < 4; i++)
#pragma unroll
    for (int j = 0; j < 4; j++) acc[i][j] = (floatx4){0.f, 0.f, 0.f, 0.f};

  for (int kk = 0; kk < 8; kk++) {
    int kb = kk*64 + klane;
#pragma unroll
    for (int kt = 0; kt < 2; kt++) {
      int kg = kb + kt*32;
      gload16(A  + arow0 + kg, alds + (kt*8 + 2*w    ) * 1024);
      gload16(A  + arow1 + kg, alds + (kt*8 + 2*w + 1) * 1024);
      gload16(Bt + brow0 + kg, blds + (kt*8 + 2*w    ) * 1024);
      gload16(Bt + brow1 + kg, blds + (kt*8 + 2*w + 1) * 1024);
    }
    __syncthreads();
#pragma unroll
    for (int kt = 0; kt < 2; kt++) {
      bf16x8 af[4], bfr[4];
#pragma unroll
      for (int i = 0; i < 4; i++) af[i]  = *(const bf16x8*)(alds + ((kt*8 + wm*4 + i)*64 + lane)*16);
#pragma unroll
      for (int j = 0; j < 4; j++) bfr[j] = *(const bf16x8*)(blds + ((kt*8 + wn*4 + j)*64 + lane)*16);
#pragma unroll
      for (int i = 0; i < 4; i++)
#pragma unroll
        for (int j = 0; j < 4; j++)
          acc[i][j] = mfma16(af[i], bfr[j], acc[i][j]);
    }
    __syncthreads();
  }
  int cl = lane & 15, rbase = (lane >> 4) * 4;
#pragma unroll
  for (int i = 0; i < 4; i++) {
    int gm = mblk*128 + wm*64 + i*16 + rbase;
#pragma unroll
    for (int j = 0; j < 4; j++) {
      int gn = nblk*128 + wn*64 + j*16 + cl;
      float bv = bias[gn];
#pragma unroll
      for (int r = 0; r < 4; r++)
        C[(size_t)(gm + r) * NH3 + gn] = __float2bfloat16(acc[i][j][r] + bv);
    }
  }
}

// =====================================================================================
// gru_scan, round 6: RUNTIME XCD-CLAIMED ROLES -> siblings provably share one XCD L2.
// Round-5 post-mortem: FETCH_SIZE dropped 183->92MB = sc0 polls were STALE L2 HITS ->
// the guessed mapping (g=bid&7) did NOT co-locate siblings; producer's plain stores sat
// in another XCD's writeback L2, invisible forever; blocks latched to the slow ald loop.
// Fix: tid0 reads HW_REG_XCC_ID (s_getreg, reg 20 [m09]) and blocks CLAIM roles:
//   k = fetch_add(claim[xcc]); k<4 -> role=(g=xcc, c=k); set bit in claimed-mask.
//   All 32 rendezvous on an arrivals counter. If any k>=4 (imbalanced dispatch), the
//   overflow blocks take the j-th missing role from the mask and a global flag forces
//   AGENT MODE (proven ald path). Role cover is always exact; correctness never depends
//   on the mapping (G16). In fast mode the round-5 machinery finally runs in its valid
//   regime: plain 16B tagged store -> shared XCD L2; batched sc0 64B poll = ~0.2us RT.
// Dual publish (plain->fbuf + 2x ast->abuf) kept: any visibility surprise degrades
// per-thread to the proven ald loop; deadflag everywhere -> never hangs, tags validate.
// =====================================================================================
__global__ void __launch_bounds__(512, 2) gru_scan_kernel(
    const bf16*  __restrict__ wuT,   // [NH3][NH] bf16 (this layer)
    const float* __restrict__ br,    // [NH3] recurrent bias
    const bf16*  __restrict__ xp,    // [NM][NH3] bf16, row = t*NB + b (bias folded)
    bf16*        __restrict__ seq,   // [NT+1][B][H] bf16; slot 256 on entry = prev layer h_255
    float*       __restrict__ hlast, // [B][H] fp32 carry handoff (in: prev layer, out: ours)
    float*       __restrict__ out,   // layer2: d_out; else null
    u64*         __restrict__ abuf,  // agent-scope tagged slots [2][8][512][8] u64 (proven)
    u64*         __restrict__ fbuf,  // same-XCD L2 tagged slots, same layout (fast)
    unsigned*    __restrict__ claimb,// 16 u32 for THIS dispatch: [0..7] per-XCD ctr,
                                     // [8] arrivals, [9] overflow-order, [10] ovf flag,
                                     // [11] claimed-role mask
    unsigned tagbase, int layer)     // tagbase = layer*NT
{
  __shared__ __align__(16) char h_raw[2][16384];   // dbuf B-frags: [kt(16)][lane(64)]*16B
  __shared__ volatile int deadflag;
  __shared__ int s_role, s_fast;
  int tid = threadIdx.x, lane = tid & 63, w = tid >> 6;   // 8 waves
  if (tid == 0) {
    deadflag = 0;
    unsigned xcc = get_xcc();
    unsigned k = aadd(claimb + xcc, 1u);
    int role = -1;
    if (k < 4u) {
      role = (int)(xcc * 4u + k);
      aor(claimb + 11, 1u << role);
    } else {
      aadd(claimb + 10, 1u);              // overflow flag/count
    }
    aadd(claimb + 8, 1u);                 // arrival (after bit set: SEQ_CST ordering)
    long sp = 0; bool tout = false;
    while (aldu(claimb + 8) < 32u) {
      __builtin_amdgcn_s_sleep(2);
      if (++sp > (1L << 22)) { tout = true; break; }
    }
    unsigned ovf = aldu(claimb + 10);
    if (role < 0 && !tout) {              // take the j-th missing role (deterministic)
      unsigned j = aadd(claimb + 9, 1u);
      unsigned mask = aldu(claimb + 11);
      unsigned cnt = 0;
      for (int b = 0; b < 32; ++b)
        if (!((mask >> b) & 1u)) { if (cnt == j) { role = b; break; } cnt++; }
    }
    if (role < 0) { role = (int)(blockIdx.x & 31); ovf = 1u; }   // doomed-anyway fallback
    s_role = role; s_fast = (ovf == 0u) ? 1 : 0;
  }
  __syncthreads();
  int g = s_role >> 2, c = s_role & 3;
  bool fastok = (s_fast != 0);
  int bb0 = g * 16;
  int r16 = lane & 15, h4 = lane >> 4;
  int srow = tid & 15, ssc = tid >> 4;                    // staging (row, chunk-col)

  // ---- hoist weight A-fragments (loop-invariant): 3 x 16 x bf16x8 ----
  bf16x8 wf[3][16];
  float  bv[3][4];
#pragma unroll
  for (int G = 0; G < 3; G++) {
    const bf16* wrow = wuT + ((size_t)(G*NH + c*128 + w*16 + r16)) * NH + h4*8;
#pragma unroll
    for (int kt = 0; kt < 16; kt++) wf[G][kt] = *(const bf16x8*)(wrow + kt*32);
#pragma unroll
    for (int q = 0; q < 4; q++) bv[G][q] = br[G*NH + c*128 + w*16 + h4*4 + q];
  }

  // ---- fp32 carry: this lane's 4 h-elements ----
  float hreg[4];
  if (layer == 0) {
    hreg[0] = hreg[1] = hreg[2] = hreg[3] = 0.0f;
  } else {
    const float* hsrc = hlast + (size_t)(bb0 + r16) * NH + c*128 + w*16 + h4*4;
    float4 v = *(const float4*)hsrc;          // prev kernel's output: plain load OK
    hreg[0] = v.x; hreg[1] = v.y; hreg[2] = v.z; hreg[3] = v.w;
  }

  u64* seqU = (u64*)seq;
  const size_t PARU = (size_t)8 * 512 * 8;     // 32768 u64 slots per parity (256KB)
  // producer slot pair (consumer-major layout): consumer tid' = (w*4+h4)*16 + r16,
  // chunk index within consumer = c  ->  slots tid'*8 + c*2 + {0,1}
  size_t puboff = (size_t)g*4096 + ((size_t)((w*4 + h4)*16 + r16))*8 + (size_t)(c*2);

  for (int t = 0; t < NT; t++) {
    // ---- stage h_prev [16x512] into B-fragment layout, buffer t&1 ----
    if (t == 0) {
      if (layer == 0) {
        *(int4*)(h_raw[0] + tid*32)      = (int4){0,0,0,0};
        *(int4*)(h_raw[0] + tid*32 + 16) = (int4){0,0,0,0};
      } else {   // prev layer's h_255 in seq slot 256 (previous dispatch)
        const u64* src = seqU + ((size_t)NT*NBH + (size_t)(bb0 + srow)*NH) / 4;
#pragma unroll
        for (int d = 0; d < 2; d++) {
          int sc = ssc + d*32;           // 16B chunk sc of row srow: k = sc*8..+8
          u64 q0 = ald(src + sc*2), q1 = ald(src + sc*2 + 1);
          u64* dst = (u64*)(h_raw[0] + (((sc >> 2)*64) + (sc & 3)*16 + srow)*16);
          dst[0] = q0; dst[1] = q1;
        }
      }
    } else {
      size_t coff = (size_t)(t & 1)*PARU + (size_t)g*4096 + (size_t)tid*8;
      unsigned want = tagbase + (unsigned)t;
      int w_ = (int)want;
      u64 q0 = 0, q1 = 0, q2 = 0, q3 = 0;
      bool got = false;
      if (fastok) {                       // same-XCD L2 poll: ~1 L2 RT per iteration
        const u64* fb = fbuf + coff;
        for (int it = 0; it < 64; ++it) {
          intx4 A, B2, C2, D2;
          ld64sc0(fb, A, B2, C2, D2);
          if (A.y == w_ && A.w == w_ && B2.y == w_ && B2.w == w_ &&
              C2.y == w_ && C2.w == w_ && D2.y == w_ && D2.w == w_) {
            q0 = (u64)(unsigned)A.x  | ((u64)(unsigned)A.z  << 32);
            q1 = (u64)(unsigned)B2.x | ((u64)(unsigned)B2.z << 32);
            q2 = (u64)(unsigned)C2.x | ((u64)(unsigned)C2.z << 32);
            q3 = (u64)(unsigned)D2.x | ((u64)(unsigned)D2.z << 32);
            got = true; break;
          }
        }
        if (!got) fastok = false;         // visibility surprise: latch to proven path
      }
      if (!got) {                         // round-3-proven per-slot agent atomic loads
        const u64* sb = abuf + coff;
        int it = 0;
        while (!deadflag) {
          u64 a0 = ald(sb+0), a1 = ald(sb+1), b0 = ald(sb+2), b1 = ald(sb+3);
          u64 c0 = ald(sb+4), c1 = ald(sb+5), d0 = ald(sb+6), d1 = ald(sb+7);
          bool ok = ((unsigned)(a0 >> 32) == want) & ((unsigned)(a1 >> 32) == want) &
                    ((unsigned)(b0 >> 32) == want) & ((unsigned)(b1 >> 32) == want) &
                    ((unsigned)(c0 >> 32) == want) & ((unsigned)(c1 >> 32) == want) &
                    ((unsigned)(d0 >> 32) == want) & ((unsigned)(d1 >> 32) == want);
          if (ok) {
            q0 = (u64)(unsigned)a0 | ((u64)(unsigned)a1 << 32);
            q1 = (u64)(unsigned)b0 | ((u64)(unsigned)b1 << 32);
            q2 = (u64)(unsigned)c0 | ((u64)(unsigned)c1 << 32);
            q3 = (u64)(unsigned)d0 | ((u64)(unsigned)d1 << 32);
            break;
          }
          if (++it > (1 << 17)) { deadflag = 1; break; }   // escalate: never hang
        }
      }
      // chunk j = ssc + 32k holds h cols [j*4, j*4+4) of row srow
      char* hb = h_raw[t & 1];
      int j0 = ssc, j1 = ssc + 32, j2 = ssc + 64, j3 = ssc + 96;
      *(u64*)(hb + (((j0>>3)*64 + ((j0>>1)&3)*16 + srow)*16 + (j0&1)*8)) = q0;
      *(u64*)(hb + (((j1>>3)*64 + ((j1>>1)&3)*16 + srow)*16 + (j1&1)*8)) = q1;
      *(u64*)(hb + (((j2>>3)*64 + ((j2>>1)&3)*16 + srow)*16 + (j2&1)*8)) = q2;
      *(u64*)(hb + (((j3>>3)*64 + ((j3>>1)&3)*16 + srow)*16 + (j3&1)*8)) = q3;
    }

    // xp_t prefetch (plain loads; written by an earlier dispatch) — hides under barrier/MFMA
    const u64* xq = (const u64*)(xp + ((size_t)t*NB + bb0 + r16)*NH3 + c*128 + w*16 + h4*4);
    u64 xv0 = xq[0], xv1 = xq[128], xv2 = xq[256];

    __syncthreads();                   // staging visible to all waves (only barrier/step)

    // ---- rec^T = Wu_cols x h : 3 tiles/wave, K=512, weights in registers ----
    const char* hbR = h_raw[t & 1];
    floatx4 ac0 = (floatx4){0,0,0,0}, ac1 = (floatx4){0,0,0,0}, ac2 = (floatx4){0,0,0,0};
#pragma unroll
    for (int kt = 0; kt < 16; kt++) {
      bf16x8 hb = *(const bf16x8*)(hbR + (kt*64 + lane)*16);
      ac0 = mfma16(wf[0][kt], hb, ac0);
      ac1 = mfma16(wf[1][kt], hb, ac1);
      ac2 = mfma16(wf[2][kt], hb, ac2);
    }

    // ---- gates in registers ----
    unsigned short pk[4];
#pragma unroll
    for (int q = 0; q < 4; q++) {
      float rz = ac0[q] + bv[0][q];
      float rr = ac1[q] + bv[1][q];
      float rh = ac2[q] + bv[2][q];
      float xz = b2f((unsigned short)(xv0 >> (16*q)));
      float xr = b2f((unsigned short)(xv1 >> (16*q)));
      float xh = b2f((unsigned short)(xv2 >> (16*q)));
      float z  = fsig(xz + rz);
      float r  = fsig(xr + rr);
      float hh = ftanh(xh + r * rh);
      float hn = z * hreg[q] + (1.0f - z) * hh;
      hreg[q] = hn;
      pk[q] = f2b(hn);
    }
    u64 pv; __builtin_memcpy(&pv, pk, 8);

    // ---- tagged dual publish (fast L2 16B plain store + proven agent 2x8B ast) ----
    if (t < NT - 1) {
      unsigned ptag = tagbase + (unsigned)t + 1u;
      size_t poff = puboff + (size_t)((t + 1) & 1) * PARU;
      intx4 pub;
      pub.x = (int)(unsigned)(pv & 0xffffffffu);
      pub.y = (int)ptag;
      pub.z = (int)(unsigned)(pv >> 32);
      pub.w = (int)ptag;
      *(intx4*)(fbuf + poff) = pub;                 // plain store: same-XCD L2 path
      u64 tg = (u64)ptag << 32;
      u64* pp = abuf + poff;
      ast(pp,     ((u64)(unsigned)(pv & 0xffffffffu)) | tg);
      ast(pp + 1, ((u64)(unsigned)(pv >> 32))         | tg);
    }
    // seq slot t+1 for the next layer's GEMM (plain store; dispatch-boundary coherence)
    if (layer != 2)
      seqU[((size_t)(t+1)*NBH + (size_t)(bb0 + r16)*NH)/4 + c*32 + w*4 + h4] = pv;

    if (layer == 2) {                  // fp32 chain straight into d_out [B][T][H] flat
      float* o = out + ((size_t)(bb0 + r16)*NT + t)*NH + c*128 + w*16 + h4*4;
      *(float4*)o = (float4){hreg[0], hreg[1], hreg[2], hreg[3]};
      if (t == NT - 1) {               // final state tail [B][H]
        float* o2 = out + (size_t)NM*NH + (size_t)(bb0 + r16)*NH + c*128 + w*16 + h4*4;
        *(float4*)o2 = (float4){hreg[0], hreg[1], hreg[2], hreg[3]};
      }
    } else if (t == NT - 1) {          // fp32 carry handoff for next layer (plain store)
      float* o = hlast + (size_t)(bb0 + r16)*NH + c*128 + w*16 + h4*4;
      *(float4*)o = (float4){hreg[0], hreg[1], hreg[2], hreg[3]};
    }
    // no trailing barrier: LDS dbuf + (staging(t+2) transitively follows barrier(t+1))
  }
}

extern "C" void kernel_launch(void* const* d_in, const int* in_sizes, int n_in,
                              void* d_out, int out_size, void* d_ws, size_t ws_size,
                              hipStream_t stream) {
  const float* x   = (const float*)d_in[0];
  const float* wk  = (const float*)d_in[1];
  const float* wu  = (const float*)d_in[2];
  const float* bis = (const float*)d_in[3];
  float* out = (float*)d_out;

  // workspace layout:
  //   wkT   @ 0            4,718,592   [3][1536][512] bf16
  //   wuT   @ 4,718,592    4,718,592
  //   xp    @ 9,437,184  100,663,296   [32768][1536] bf16
  //   seq   @ 110,100,480 33,685,504   [257][128][512] bf16 (xb aliases base)
  //   hlast @ 143,785,984    262,144   [128][512] fp32
  //   abuf  @ 144,048,128    524,288   [2][8][512][8] u64 tagged slots (agent, proven)
  //   fbuf  @ 144,572,416    524,288   same layout (same-XCD L2 fast path)
  //   claim @ 145,096,704        256   3 layers x 16 u32 role-claim regions
  const size_t REQ = 145096960;
  if (ws_size < REQ) {
    hipMemsetAsync(d_out, 0, (size_t)out_size * 4, stream);
    return;
  }
  char* ws = (char*)d_ws;
  bf16*  wkT   = (bf16*)(ws);
  bf16*  wuT   = (bf16*)(ws + 4718592);
  bf16*  xp    = (bf16*)(ws + 9437184);
  bf16*  seq   = (bf16*)(ws + 110100480);
  bf16*  xb    = seq;                          // alias: dead after layer-0 GEMM
  float* hlast = (float*)(ws + 143785984);
  u64*   abuf  = (u64*)(ws + 144048128);
  u64*   fbuf  = (u64*)(ws + 144572416);
  unsigned* claim = (unsigned*)(ws + 145096704);

  hipMemsetAsync(abuf, 0, 1048576, stream);    // zero both tag buffers (no replay aliasing)
  hipMemsetAsync(claim, 0, 256, stream);       // zero claim regions
  transpose_cvt_kernel<<<dim3(48,16,3), dim3(32,8), 0, stream>>>(wk, wkT);
  transpose_cvt_kernel<<<dim3(48,16,3), dim3(32,8), 0, stream>>>(wu, wuT);
  cvt_x_kernel<<<(NM*NH/4)/256, 256, 0, stream>>>(x, xb);

  const size_t WS = (size_t)NH3 * NH;   // per-layer weight stride

  // layer 0
  gemm_xp_kernel<<<dim3(256,12), 256, 0, stream>>>(xb, wkT, bis + 0*2*NH3, xp, 0);
  gru_scan_kernel<<<32, 512, 0, stream>>>(wuT, bis + 0*2*NH3 + NH3, xp,
      seq, hlast, nullptr, abuf, fbuf, claim + 0, 0u, 0);
  // layer 1 (gemm reads seq slots 1..256 = layer-0 h)
  gemm_xp_kernel<<<dim3(256,12), 256, 0, stream>>>(seq + NBH, wkT + WS, bis + 1*2*NH3, xp, 1);
  gru_scan_kernel<<<32, 512, 0, stream>>>(wuT + WS, bis + 1*2*NH3 + NH3, xp,
      seq, hlast, nullptr, abuf, fbuf, claim + 16, 256u, 1);
  // layer 2 (fp32 chain straight into d_out)
  gemm_xp_kernel<<<dim3(256,12), 256, 0, stream>>>(seq + NBH, wkT + 2*WS, bis + 2*2*NH3, xp, 1);
  gru_scan_kernel<<<32, 512, 0, stream>>>(wuT + 2*WS, bis + 2*2*NH3 + NH3, xp,
      seq, hlast, out, abuf, fbuf, claim + 32, 512u, 2);

  (void)in_sizes; (void)n_in; (void)out_size; (void)ws_size;
}

// Round 7
// 3556.462 us; speedup vs baseline: 1.4198x; 1.4198x over previous
//
#include <hip/hip_runtime.h>
#include <hip/hip_bf16.h>

#define NL  3
#define NB  128
#define NT  256
#define NH  512
#define NH3 1536
#define NBH (NB*NH)      // 65536
#define NM  (NB*NT)      // 32768

typedef __bf16 bf16x8 __attribute__((ext_vector_type(8)));
typedef float  floatx4 __attribute__((ext_vector_type(4)));
typedef int    intx4  __attribute__((ext_vector_type(4)));
typedef __hip_bfloat16 bf16;
typedef unsigned long long u64;

__device__ __forceinline__ floatx4 mfma16(bf16x8 a, bf16x8 b, floatx4 c) {
  return __builtin_amdgcn_mfma_f32_16x16x32_bf16(a, b, c, 0, 0, 0);
}
__device__ __forceinline__ void gload16(const void* g, void* l) {
  __builtin_amdgcn_global_load_lds(
      (const __attribute__((address_space(1))) unsigned int*)g,
      (__attribute__((address_space(3))) unsigned int*)l, 16, 0, 0);
}
__device__ __forceinline__ float fsig(float x)  { return 1.0f / (1.0f + __expf(-x)); }
__device__ __forceinline__ float ftanh(float x) { return 2.0f / (1.0f + __expf(-2.0f*x)) - 1.0f; }
__device__ __forceinline__ float b2f(unsigned short u) {
  unsigned v = (unsigned)u << 16; float f; __builtin_memcpy(&f, &v, 4); return f;
}
__device__ __forceinline__ unsigned short f2b(float f) {
  bf16 h = __float2bfloat16(f); unsigned short u; __builtin_memcpy(&u, &h, 2); return u;
}
__device__ __forceinline__ u64 ald(const u64* p) {
  return __hip_atomic_load(p, __ATOMIC_RELAXED, __HIP_MEMORY_SCOPE_AGENT);
}
__device__ __forceinline__ void ast(u64* p, u64 v) {
  __hip_atomic_store(p, v, __ATOMIC_RELAXED, __HIP_MEMORY_SCOPE_AGENT);
}

// Batched poll of 4 slots (16B each) at 4 independent addresses; single waitcnt = 1 RT.
// sc1 loads proven (round 4) to observe ast (agent-scope) stores.
__device__ __forceinline__ void ld4x16(const void* p0, const void* p1,
                                       const void* p2, const void* p3,
                                       intx4& a, intx4& b, intx4& c, intx4& d) {
  asm volatile(
      "global_load_dwordx4 %0, %4, off sc1\n\t"
      "global_load_dwordx4 %1, %5, off sc1\n\t"
      "global_load_dwordx4 %2, %6, off sc1\n\t"
      "global_load_dwordx4 %3, %7, off sc1\n\t"
      "s_waitcnt vmcnt(0)"
      : "=&v"(a), "=&v"(b), "=&v"(c), "=&v"(d)
      : "v"(p0), "v"(p1), "v"(p2), "v"(p3)
      : "memory");
}

// ---------- transpose + cvt weights: fp32 [NL][NH][NH3] -> bf16 [NL][NH3][NH] ----------
__global__ void transpose_cvt_kernel(const float* __restrict__ in, bf16* __restrict__ out) {
  __shared__ float tile[32][33];
  int l = blockIdx.z;
  int n0 = blockIdx.x * 32, k0 = blockIdx.y * 32;
  const float* src = in + (size_t)l * NH * NH3;
  bf16* dst = out + (size_t)l * NH3 * NH;
  int tx = threadIdx.x, ty = threadIdx.y;    // 32 x 8
#pragma unroll
  for (int i = 0; i < 4; i++)
    tile[ty + 8*i][tx] = src[(size_t)(k0 + ty + 8*i) * NH3 + n0 + tx];
  __syncthreads();
#pragma unroll
  for (int i = 0; i < 4; i++)
    dst[(size_t)(n0 + ty + 8*i) * NH + k0 + tx] = __float2bfloat16(tile[tx][ty + 8*i]);
}

// ---------- elementwise fp32 -> bf16 (x input) ----------
__global__ void cvt_x_kernel(const float* __restrict__ in, bf16* __restrict__ out) {
  size_t i = (size_t)blockIdx.x * blockDim.x + threadIdx.x;
  float4 v = ((const float4*)in)[i];
  ushort4 pk;
  pk.x = f2b(v.x); pk.y = f2b(v.y); pk.z = f2b(v.z); pk.w = f2b(v.w);
  ((ushort4*)out)[i] = pk;
}

// ---------- xp GEMM (proven): C[m][n] = A[m]@Bt[n]^T + bias[n], bf16 out ----------
__global__ void __launch_bounds__(256, 2) gemm_xp_kernel(
    const bf16* __restrict__ A, const bf16* __restrict__ Bt,
    const float* __restrict__ bias, bf16* __restrict__ C, int a_mode)
{
  __shared__ char alds[16384];
  __shared__ char blds[16384];
  int tid = threadIdx.x;
  int lane = tid & 63, w = tid >> 6;
  int mblk = blockIdx.x, nblk = blockIdx.y;
  int wm = w >> 1, wn = w & 1;
  int klane = (lane >> 4) * 8;
  int r0 = 2*w*16 + (lane & 15);
  size_t arow0, arow1;
  if (a_mode == 0) {
    arow0 = ((size_t)r0 * NT + mblk) * NH;
    arow1 = ((size_t)(r0 + 16) * NT + mblk) * NH;
  } else {
    arow0 = (size_t)(mblk*128 + r0) * NH;
    arow1 = arow0 + (size_t)16 * NH;
  }
  size_t brow0 = (size_t)(nblk*128 + 2*w*16 + (lane & 15)) * NH;
  size_t brow1 = brow0 + (size_t)16 * NH;

  floatx4 acc[4][4];
#pragma unroll
  for (int i = 0; i < 4; i++)
#pragma unroll
    for (int j = 0; j < 4; j++) acc[i][j] = (floatx4){0.f, 0.f, 0.f, 0.f};

  for (int kk = 0; kk < 8; kk++) {
    int kb = kk*64 + klane;
#pragma unroll
    for (int kt = 0; kt < 2; kt++) {
      int kg = kb + kt*32;
      gload16(A  + arow0 + kg, alds + (kt*8 + 2*w    ) * 1024);
      gload16(A  + arow1 + kg, alds + (kt*8 + 2*w + 1) * 1024);
      gload16(Bt + brow0 + kg, blds + (kt*8 + 2*w    ) * 1024);
      gload16(Bt + brow1 + kg, blds + (kt*8 + 2*w + 1) * 1024);
    }
    __syncthreads();
#pragma unroll
    for (int kt = 0; kt < 2; kt++) {
      bf16x8 af[4], bfr[4];
#pragma unroll
      for (int i = 0; i < 4; i++) af[i]  = *(const bf16x8*)(alds + ((kt*8 + wm*4 + i)*64 + lane)*16);
#pragma unroll
      for (int j = 0; j < 4; j++) bfr[j] = *(const bf16x8*)(blds + ((kt*8 + wn*4 + j)*64 + lane)*16);
#pragma unroll
      for (int i = 0; i < 4; i++)
#pragma unroll
        for (int j = 0; j < 4; j++)
          acc[i][j] = mfma16(af[i], bfr[j], acc[i][j]);
    }
    __syncthreads();
  }
  int cl = lane & 15, rbase = (lane >> 4) * 4;
#pragma unroll
  for (int i = 0; i < 4; i++) {
    int gm = mblk*128 + wm*64 + i*16 + rbase;
#pragma unroll
    for (int j = 0; j < 4; j++) {
      int gn = nblk*128 + wn*64 + j*16 + cl;
      float bv = bias[gn];
#pragma unroll
      for (int r = 0; r < 4; r++)
        C[(size_t)(gm + r) * NH3 + gn] = __float2bfloat16(acc[i][j][r] + bv);
    }
  }
}

// =====================================================================================
// gru_scan, round 7: DOUBLY-COALESCED tagged exchange, proven primitives only.
// Round-6 post-mortem: claim protocol detected imbalanced dispatch -> forced slow path;
// same-XCD L2 exchange abandoned (two mapping strategies both failed). Fresh read of
// R1-R6: the constant across all slow variants is the PRODUCER side - 1024 scattered 8B
// agent stores per block per step = 32K fabric transactions/step saturating the LLC.
// Fix: slot permutation making BOTH sides contiguous:
//   slotidx = c*512 + w*64 + lane   (16B slot = {d0,tag,d1,tag})
//   producer wave (g,c,w): 64 consecutive slots = 1KB contiguous (ast pairs merge into
//   ~32 line-transactions vs 128 scattered); consumer thread needs chunks j=k*32+ssc
//   which sit at k*512 + w*64 + lane -> consumer wave w reads 4 x 1KB contiguous runs
//   (= producer wave w's line from each of the 4 siblings, incl itself).
// Publish: 2x ast per thread (proven). Poll: batched 4x dwordx4 sc1, one waitcnt = 1 RT
// (sc1-sees-ast proven in round 4); per-thread latch to proven ald loop on the SAME
// addresses (no dual buffer) + deadflag -> never hangs, worst case ~ round-3/4 perf.
// No claim protocol, no XCD assumption. Parity-dbuf ABA argument unchanged (R4 passed).
// LDS h_raw dbuf -> ONE __syncthreads per step; my own store-drain at that barrier
// overlaps the sibling-poll wait of the next step.
// =====================================================================================
__global__ void __launch_bounds__(512, 2) gru_scan_kernel(
    const bf16*  __restrict__ wuT,   // [NH3][NH] bf16 (this layer)
    const float* __restrict__ br,    // [NH3] recurrent bias
    const bf16*  __restrict__ xp,    // [NM][NH3] bf16, row = t*NB + b (bias folded)
    bf16*        __restrict__ seq,   // [NT+1][B][H] bf16; slot 256 on entry = prev layer h_255
    float*       __restrict__ hlast, // [B][H] fp32 carry handoff (in: prev layer, out: ours)
    float*       __restrict__ out,   // layer2: d_out; else null
    u64*         __restrict__ fbuf,  // [2 parity][8 grp][2048 slots] x 16B {d0,tag,d1,tag}
    unsigned tagbase, int layer)     // tagbase = layer*NT
{
  __shared__ __align__(16) char h_raw[2][16384];   // dbuf B-frags: [kt(16)][lane(64)]*16B
  __shared__ volatile int deadflag;
  int tid = threadIdx.x, lane = tid & 63, w = tid >> 6;   // 8 waves
  int g = blockIdx.x >> 2, c = blockIdx.x & 3;
  int bb0 = g * 16;
  int r16 = lane & 15, h4 = lane >> 4;
  int srow = tid & 15, ssc = tid >> 4;                    // staging (row, chunk-col)
  if (tid == 0) deadflag = 0;

  // ---- hoist weight A-fragments (loop-invariant): 3 x 16 x bf16x8 ----
  bf16x8 wf[3][16];
  float  bv[3][4];
#pragma unroll
  for (int G = 0; G < 3; G++) {
    const bf16* wrow = wuT + ((size_t)(G*NH + c*128 + w*16 + r16)) * NH + h4*8;
#pragma unroll
    for (int kt = 0; kt < 16; kt++) wf[G][kt] = *(const bf16x8*)(wrow + kt*32);
#pragma unroll
    for (int q = 0; q < 4; q++) bv[G][q] = br[G*NH + c*128 + w*16 + h4*4 + q];
  }

  // ---- fp32 carry: this lane's 4 h-elements ----
  float hreg[4];
  if (layer == 0) {
    hreg[0] = hreg[1] = hreg[2] = hreg[3] = 0.0f;
  } else {
    const float* hsrc = hlast + (size_t)(bb0 + r16) * NH + c*128 + w*16 + h4*4;
    float4 v = *(const float4*)hsrc;          // prev kernel's output: plain load OK
    hreg[0] = v.x; hreg[1] = v.y; hreg[2] = v.z; hreg[3] = v.w;
  }

  u64* seqU = (u64*)seq;
  const size_t PARU = (size_t)8 * 2048 * 2;    // u64 per parity (256KB)
  const size_t GRPU = (size_t)2048 * 2;        // u64 per group
  // producer slot pair: slotidx = c*512 + w*64 + lane
  size_t puboff = (size_t)g*GRPU + (size_t)(c*512 + w*64 + lane)*2;
  // consumer slot pairs: k*512 + w*64 + lane, k = 0..3 (chunk j = k*32 + ssc)
  size_t cbase  = (size_t)g*GRPU + (size_t)(w*64 + lane)*2;
  bool fastok = true;

  for (int t = 0; t < NT; t++) {
    // ---- stage h_prev [16x512] into B-fragment layout, buffer t&1 ----
    if (t == 0) {
      if (layer == 0) {
        *(int4*)(h_raw[0] + tid*32)      = (int4){0,0,0,0};
        *(int4*)(h_raw[0] + tid*32 + 16) = (int4){0,0,0,0};
      } else {   // prev layer's h_255 in seq slot 256 (previous dispatch)
        const u64* src = seqU + ((size_t)NT*NBH + (size_t)(bb0 + srow)*NH) / 4;
#pragma unroll
        for (int d = 0; d < 2; d++) {
          int sc = ssc + d*32;           // 16B chunk sc of row srow: k = sc*8..+8
          u64 q0 = ald(src + sc*2), q1 = ald(src + sc*2 + 1);
          u64* dst = (u64*)(h_raw[0] + (((sc >> 2)*64) + (sc & 3)*16 + srow)*16);
          dst[0] = q0; dst[1] = q1;
        }
      }
    } else {
      const u64* pb = fbuf + (size_t)(t & 1)*PARU + cbase;
      unsigned want = tagbase + (unsigned)t;
      int w_ = (int)want;
      u64 q0 = 0, q1 = 0, q2 = 0, q3 = 0;
      bool got = false;
      if (fastok) {                       // batched 1-RT poll, both sides coalesced
        const void* p0 = (const void*)(pb);
        const void* p1 = (const void*)(pb + 1024);   // +512 slots
        const void* p2 = (const void*)(pb + 2048);
        const void* p3 = (const void*)(pb + 3072);
        for (int it = 0; it < 64; ++it) {
          intx4 A, B2, C2, D2;
          ld4x16(p0, p1, p2, p3, A, B2, C2, D2);
          if (A.y == w_ && A.w == w_ && B2.y == w_ && B2.w == w_ &&
              C2.y == w_ && C2.w == w_ && D2.y == w_ && D2.w == w_) {
            q0 = (u64)(unsigned)A.x  | ((u64)(unsigned)A.z  << 32);
            q1 = (u64)(unsigned)B2.x | ((u64)(unsigned)B2.z << 32);
            q2 = (u64)(unsigned)C2.x | ((u64)(unsigned)C2.z << 32);
            q3 = (u64)(unsigned)D2.x | ((u64)(unsigned)D2.z << 32);
            got = true; break;
          }
        }
        if (!got) fastok = false;         // latch to proven path (same addresses)
      }
      if (!got) {                         // round-3-proven per-slot agent atomic loads
        int it = 0;
        while (!deadflag) {
          u64 a0 = ald(pb+0),    a1 = ald(pb+1);
          u64 b0 = ald(pb+1024), b1 = ald(pb+1025);
          u64 c0 = ald(pb+2048), c1 = ald(pb+2049);
          u64 d0 = ald(pb+3072), d1 = ald(pb+3073);
          bool ok = ((unsigned)(a0 >> 32) == want) & ((unsigned)(a1 >> 32) == want) &
                    ((unsigned)(b0 >> 32) == want) & ((unsigned)(b1 >> 32) == want) &
                    ((unsigned)(c0 >> 32) == want) & ((unsigned)(c1 >> 32) == want) &
                    ((unsigned)(d0 >> 32) == want) & ((unsigned)(d1 >> 32) == want);
          if (ok) {
            q0 = (u64)(unsigned)a0 | ((u64)(unsigned)a1 << 32);
            q1 = (u64)(unsigned)b0 | ((u64)(unsigned)b1 << 32);
            q2 = (u64)(unsigned)c0 | ((u64)(unsigned)c1 << 32);
            q3 = (u64)(unsigned)d0 | ((u64)(unsigned)d1 << 32);
            break;
          }
          if (++it > (1 << 17)) { deadflag = 1; break; }   // escalate: never hang
        }
      }
      // load k delivers chunk j = k*32 + ssc (h cols j*4..+4 of row srow)
      char* hb = h_raw[t & 1];
      int j0 = ssc, j1 = ssc + 32, j2 = ssc + 64, j3 = ssc + 96;
      *(u64*)(hb + (((j0>>3)*64 + ((j0>>1)&3)*16 + srow)*16 + (j0&1)*8)) = q0;
      *(u64*)(hb + (((j1>>3)*64 + ((j1>>1)&3)*16 + srow)*16 + (j1&1)*8)) = q1;
      *(u64*)(hb + (((j2>>3)*64 + ((j2>>1)&3)*16 + srow)*16 + (j2&1)*8)) = q2;
      *(u64*)(hb + (((j3>>3)*64 + ((j3>>1)&3)*16 + srow)*16 + (j3&1)*8)) = q3;
    }

    // xp_t prefetch (plain loads; written by an earlier dispatch) — hides under barrier/MFMA
    const u64* xq = (const u64*)(xp + ((size_t)t*NB + bb0 + r16)*NH3 + c*128 + w*16 + h4*4);
    u64 xv0 = xq[0], xv1 = xq[128], xv2 = xq[256];

    __syncthreads();                   // staging visible to all waves (only barrier/step)

    // ---- rec^T = Wu_cols x h : 3 tiles/wave, K=512, weights in registers ----
    const char* hbR = h_raw[t & 1];
    floatx4 ac0 = (floatx4){0,0,0,0}, ac1 = (floatx4){0,0,0,0}, ac2 = (floatx4){0,0,0,0};
#pragma unroll
    for (int kt = 0; kt < 16; kt++) {
      bf16x8 hb = *(const bf16x8*)(hbR + (kt*64 + lane)*16);
      ac0 = mfma16(wf[0][kt], hb, ac0);
      ac1 = mfma16(wf[1][kt], hb, ac1);
      ac2 = mfma16(wf[2][kt], hb, ac2);
    }

    // ---- gates in registers ----
    unsigned short pk[4];
#pragma unroll
    for (int q = 0; q < 4; q++) {
      float rz = ac0[q] + bv[0][q];
      float rr = ac1[q] + bv[1][q];
      float rh = ac2[q] + bv[2][q];
      float xz = b2f((unsigned short)(xv0 >> (16*q)));
      float xr = b2f((unsigned short)(xv1 >> (16*q)));
      float xh = b2f((unsigned short)(xv2 >> (16*q)));
      float z  = fsig(xz + rz);
      float r  = fsig(xr + rr);
      float hh = ftanh(xh + r * rh);
      float hn = z * hreg[q] + (1.0f - z) * hh;
      hreg[q] = hn;
      pk[q] = f2b(hn);
    }
    u64 pv; __builtin_memcpy(&pv, pk, 8);

    // ---- tagged publish: 2x 8B ast, wave-contiguous 1KB window (fire-and-forget) ----
    if (t < NT - 1) {
      u64 tg = (u64)(tagbase + (unsigned)t + 1u) << 32;
      u64* pp = fbuf + (size_t)((t + 1) & 1)*PARU + puboff;
      ast(pp,     ((u64)(unsigned)(pv & 0xffffffffu)) | tg);
      ast(pp + 1, ((u64)(unsigned)(pv >> 32))         | tg);
    }
    // seq slot t+1 for the next layer's GEMM (plain store; dispatch-boundary coherence)
    if (layer != 2)
      seqU[((size_t)(t+1)*NBH + (size_t)(bb0 + r16)*NH)/4 + c*32 + w*4 + h4] = pv;

    if (layer == 2) {                  // fp32 chain straight into d_out [B][T][H] flat
      float* o = out + ((size_t)(bb0 + r16)*NT + t)*NH + c*128 + w*16 + h4*4;
      *(float4*)o = (float4){hreg[0], hreg[1], hreg[2], hreg[3]};
      if (t == NT - 1) {               // final state tail [B][H]
        float* o2 = out + (size_t)NM*NH + (size_t)(bb0 + r16)*NH + c*128 + w*16 + h4*4;
        *(float4*)o2 = (float4){hreg[0], hreg[1], hreg[2], hreg[3]};
      }
    } else if (t == NT - 1) {          // fp32 carry handoff for next layer (plain store)
      float* o = hlast + (size_t)(bb0 + r16)*NH + c*128 + w*16 + h4*4;
      *(float4*)o = (float4){hreg[0], hreg[1], hreg[2], hreg[3]};
    }
    // no trailing barrier: LDS dbuf + (staging(t+2) transitively follows barrier(t+1))
  }
}

extern "C" void kernel_launch(void* const* d_in, const int* in_sizes, int n_in,
                              void* d_out, int out_size, void* d_ws, size_t ws_size,
                              hipStream_t stream) {
  const float* x   = (const float*)d_in[0];
  const float* wk  = (const float*)d_in[1];
  const float* wu  = (const float*)d_in[2];
  const float* bis = (const float*)d_in[3];
  float* out = (float*)d_out;

  // workspace layout:
  //   wkT   @ 0            4,718,592   [3][1536][512] bf16
  //   wuT   @ 4,718,592    4,718,592
  //   xp    @ 9,437,184  100,663,296   [32768][1536] bf16
  //   seq   @ 110,100,480 33,685,504   [257][128][512] bf16 (xb aliases base)
  //   hlast @ 143,785,984    262,144   [128][512] fp32
  //   fbuf  @ 144,048,128    524,288   [2][8][2048] x 16B tagged slots (doubly-coalesced)
  const size_t REQ = 144572416;
  if (ws_size < REQ) {
    hipMemsetAsync(d_out, 0, (size_t)out_size * 4, stream);
    return;
  }
  char* ws = (char*)d_ws;
  bf16*  wkT   = (bf16*)(ws);
  bf16*  wuT   = (bf16*)(ws + 4718592);
  bf16*  xp    = (bf16*)(ws + 9437184);
  bf16*  seq   = (bf16*)(ws + 110100480);
  bf16*  xb    = seq;                          // alias: dead after layer-0 GEMM
  float* hlast = (float*)(ws + 143785984);
  u64*   fbuf  = (u64*)(ws + 144048128);

  hipMemsetAsync(fbuf, 0, 524288, stream);     // zero tags: no cross-replay aliasing
  transpose_cvt_kernel<<<dim3(48,16,3), dim3(32,8), 0, stream>>>(wk, wkT);
  transpose_cvt_kernel<<<dim3(48,16,3), dim3(32,8), 0, stream>>>(wu, wuT);
  cvt_x_kernel<<<(NM*NH/4)/256, 256, 0, stream>>>(x, xb);

  const size_t WS = (size_t)NH3 * NH;   // per-layer weight stride

  // layer 0
  gemm_xp_kernel<<<dim3(256,12), 256, 0, stream>>>(xb, wkT, bis + 0*2*NH3, xp, 0);
  gru_scan_kernel<<<32, 512, 0, stream>>>(wuT, bis + 0*2*NH3 + NH3, xp,
      seq, hlast, nullptr, fbuf, 0u, 0);
  // layer 1 (gemm reads seq slots 1..256 = layer-0 h)
  gemm_xp_kernel<<<dim3(256,12), 256, 0, stream>>>(seq + NBH, wkT + WS, bis + 1*2*NH3, xp, 1);
  gru_scan_kernel<<<32, 512, 0, stream>>>(wuT + WS, bis + 1*2*NH3 + NH3, xp,
      seq, hlast, nullptr, fbuf, 256u, 1);
  // layer 2 (fp32 chain straight into d_out)
  gemm_xp_kernel<<<dim3(256,12), 256, 0, stream>>>(seq + NBH, wkT + 2*WS, bis + 2*2*NH3, xp, 1);
  gru_scan_kernel<<<32, 512, 0, stream>>>(wuT + 2*WS, bis + 2*2*NH3 + NH3, xp,
      seq, hlast, out, fbuf, 512u, 2);

  (void)in_sizes; (void)n_in; (void)out_size; (void)ws_size;
}